// Round 3
// baseline (220.541 us; speedup 1.0000x reference)
//
#include <hip/hip_runtime.h>
#include <hip/hip_bf16.h>

#define B_ 8
#define C_ 128
#define N_ 4096   // H*W = 64*64

typedef __bf16 bf16x8 __attribute__((ext_vector_type(8)));
typedef float  f32x4  __attribute__((ext_vector_type(4)));
typedef unsigned short u16x8 __attribute__((ext_vector_type(8)));

// ---------------------------------------------------------------------------
// Kernel 1: channel softmax over C for each (b, n), x held in registers.
//   writes xs (fp32, nontemporal) into the "out" region of d_out [b][c][n]
//   writes vT (bf16) into workspace [b][n][c]
//   also zeroes rsum[idx] (one entry per thread) for kernel 2's atomics.
// ---------------------------------------------------------------------------
__global__ __launch_bounds__(256) void chan_softmax(const float* __restrict__ x,
                                                    float* __restrict__ xs,
                                                    __hip_bfloat16* __restrict__ vT,
                                                    float* __restrict__ rsum)
{
    int idx = blockIdx.x * 256 + threadIdx.x;     // (b, n) flattened, 32768 total
    rsum[idx] = 0.0f;

    int b = idx >> 12;
    int n = idx & (N_ - 1);

    const float* xp = x + (size_t)b * C_ * N_ + n;

    float xv[C_];
    #pragma unroll
    for (int c = 0; c < C_; ++c) xv[c] = xp[(size_t)c * N_];   // independent loads

    float m = xv[0];
    #pragma unroll
    for (int c = 1; c < C_; ++c) m = fmaxf(m, xv[c]);

    float s = 0.f;
    #pragma unroll
    for (int c = 0; c < C_; ++c) { xv[c] = __expf(xv[c] - m); s += xv[c]; }
    float inv = 1.f / s;

    float* op = xs + (size_t)b * C_ * N_ + n;
    u16x8* vp = reinterpret_cast<u16x8*>(vT + ((size_t)b * N_ + n) * C_);

    #pragma unroll
    for (int c0 = 0; c0 < C_; c0 += 8) {
        u16x8 pk;
        #pragma unroll
        for (int j = 0; j < 8; ++j) {
            float v = xv[c0 + j] * inv;
            __builtin_nontemporal_store(v, &op[(size_t)(c0 + j) * N_]);
            __hip_bfloat16 hb = __float2bfloat16(v);
            pk[j] = *reinterpret_cast<unsigned short*>(&hb);
        }
        vp[c0 >> 3] = pk;
    }
}

// ---------------------------------------------------------------------------
// Kernel 2: rsum[b][i] = sum_j exp(<v_i, v_j>), exploiting e_ij = e_ji.
// Block = (batch, 64-row stripe s). Only tiles (s, j) with j >= s are computed
// (upper triangle): row-sums accumulate locally; col-sums of off-diagonal
// tiles are the transposed contribution and go to rows of stripe j via
// device-scope atomicAdd. e in [0,1] -> no max subtraction needed.
// Stripe map pairs heavy+light stripes (s + s' tiles = 33 per block pair).
// ---------------------------------------------------------------------------
__global__ __launch_bounds__(256, 2) void rsum_sym(const __hip_bfloat16* __restrict__ vT,
                                                   float* __restrict__ rsum)
{
    int bid  = blockIdx.x;
    int b    = bid & 7;                      // batch pinned to XCD
    int sraw = bid >> 3;
    int s    = (sraw < 32) ? sraw : 95 - sraw;   // load-balance bijection

    int w    = threadIdx.x >> 6;
    int lane = threadIdx.x & 63;
    int r16  = lane & 15;
    int kg   = lane >> 4;

    const __hip_bfloat16* base = vT + (size_t)b * N_ * C_;
    float* rb = rsum + (size_t)b * N_;

    // A fragments: stripe rows, full K=128 (64 VGPR), live for all tiles.
    bf16x8 a[4][4];
    #pragma unroll
    for (int mi = 0; mi < 4; ++mi)
        #pragma unroll
        for (int ks = 0; ks < 4; ++ks)
            a[mi][ks] = *reinterpret_cast<const bf16x8*>(
                base + (size_t)(s * 64 + mi * 16 + r16) * C_ + ks * 32 + kg * 8);

    float rs[4][4] = {};   // row-sum accum (mi, r)

    for (int j = s + w; j < 64; j += 4) {
        f32x4 acc[4][4] = {};
        #pragma unroll
        for (int ks = 0; ks < 4; ++ks) {
            bf16x8 bb[4];
            #pragma unroll
            for (int nj = 0; nj < 4; ++nj)
                bb[nj] = *reinterpret_cast<const bf16x8*>(
                    base + (size_t)(j * 64 + nj * 16 + r16) * C_ + ks * 32 + kg * 8);
            #pragma unroll
            for (int mi = 0; mi < 4; ++mi)
                #pragma unroll
                for (int nj = 0; nj < 4; ++nj)
                    acc[mi][nj] = __builtin_amdgcn_mfma_f32_16x16x32_bf16(
                        a[mi][ks], bb[nj], acc[mi][nj], 0, 0, 0);
        }

        float cs[4] = {};
        #pragma unroll
        for (int mi = 0; mi < 4; ++mi)
            #pragma unroll
            for (int nj = 0; nj < 4; ++nj)
                #pragma unroll
                for (int r = 0; r < 4; ++r) {
                    float e = __expf(acc[mi][nj][r]);
                    rs[mi][r] += e;
                    cs[nj] += e;
                }

        if (j != s) {
            // col-sums -> transposed row-sum contribution for stripe j
            #pragma unroll
            for (int nj = 0; nj < 4; ++nj) {
                cs[nj] += __shfl_xor(cs[nj], 16, 64);
                cs[nj] += __shfl_xor(cs[nj], 32, 64);
            }
            if (lane < 16)
                #pragma unroll
                for (int nj = 0; nj < 4; ++nj)
                    atomicAdd(&rb[j * 64 + nj * 16 + r16], cs[nj]);
        }
    }

    // row-sums: reduce over the 16 column-slice lanes
    #pragma unroll
    for (int off = 1; off < 16; off <<= 1)
        #pragma unroll
        for (int mi = 0; mi < 4; ++mi)
            #pragma unroll
            for (int r = 0; r < 4; ++r)
                rs[mi][r] += __shfl_xor(rs[mi][r], off, 64);

    if (r16 == 0)
        #pragma unroll
        for (int mi = 0; mi < 4; ++mi)
            #pragma unroll
            for (int r = 0; r < 4; ++r)
                atomicAdd(&rb[s * 64 + mi * 16 + kg * 4 + r], rs[mi][r]);
}

// ---------------------------------------------------------------------------
// Kernel 3: attention[b][i][j] = exp(<v_i,v_j>) / rsum[b][i], streamed out.
// 32-row stripes, ~105 VGPR -> 4 waves/SIMD for store-queue saturation.
// Nontemporal stores keep vT panels L2-resident.
// ---------------------------------------------------------------------------
__global__ __launch_bounds__(256, 4) void att_write(const __hip_bfloat16* __restrict__ vT,
                                                    const float* __restrict__ rsum,
                                                    float* __restrict__ att)
{
    int bid = blockIdx.x;
    int b   = bid & 7;
    int rowbase = (bid >> 3) * 32;

    int w    = threadIdx.x >> 6;
    int lane = threadIdx.x & 63;
    int r16  = lane & 15;
    int kg   = lane >> 4;

    const __hip_bfloat16* base = vT + (size_t)b * N_ * C_;

    bf16x8 a[2][4];
    #pragma unroll
    for (int mi = 0; mi < 2; ++mi)
        #pragma unroll
        for (int ks = 0; ks < 4; ++ks)
            a[mi][ks] = *reinterpret_cast<const bf16x8*>(
                base + (size_t)(rowbase + mi * 16 + r16) * C_ + ks * 32 + kg * 8);

    float inv[2][4];
    #pragma unroll
    for (int mi = 0; mi < 2; ++mi)
        #pragma unroll
        for (int r = 0; r < 4; ++r)
            inv[mi][r] = 1.f / rsum[(size_t)b * N_ + rowbase + mi * 16 + kg * 4 + r];

    float* ab = att + (size_t)b * N_ * N_;

    #pragma unroll 1
    for (int jt = 0; jt < 16; ++jt) {
        int colbase = jt * 256 + w * 64;
        f32x4 acc[2][4] = {};
        #pragma unroll
        for (int ks = 0; ks < 4; ++ks) {
            bf16x8 bb[4];
            #pragma unroll
            for (int nj = 0; nj < 4; ++nj)
                bb[nj] = *reinterpret_cast<const bf16x8*>(
                    base + (size_t)(colbase + nj * 16 + r16) * C_ + ks * 32 + kg * 8);
            #pragma unroll
            for (int mi = 0; mi < 2; ++mi)
                #pragma unroll
                for (int nj = 0; nj < 4; ++nj)
                    acc[mi][nj] = __builtin_amdgcn_mfma_f32_16x16x32_bf16(
                        a[mi][ks], bb[nj], acc[mi][nj], 0, 0, 0);
        }
        #pragma unroll
        for (int mi = 0; mi < 2; ++mi) {
            int row = rowbase + mi * 16 + kg * 4;
            #pragma unroll
            for (int nj = 0; nj < 4; ++nj) {
                int col = colbase + nj * 16 + r16;
                #pragma unroll
                for (int r = 0; r < 4; ++r)
                    __builtin_nontemporal_store(__expf(acc[mi][nj][r]) * inv[mi][r],
                                                &ab[(size_t)(row + r) * N_ + col]);
            }
        }
    }
}

// ---------------------------------------------------------------------------
// Kernel 4: out = gamma * (V @ attention^T) + xs. gamma==0 in the benchmark
// -> immediate exit; general path is a correct fallback.
// ---------------------------------------------------------------------------
__global__ __launch_bounds__(128) void pv_update(const float* __restrict__ gamma,
                                                 const __hip_bfloat16* __restrict__ vT,
                                                 const float* __restrict__ att,
                                                 float* __restrict__ out)
{
    float g = gamma[0];
    if (g == 0.0f) return;

    int b = blockIdx.y;
    int n = blockIdx.x;
    int c = threadIdx.x;   // 128

    const float* arow = att + ((size_t)b * N_ + n) * N_;
    const __hip_bfloat16* vb = vT + (size_t)b * N_ * C_;

    float acc = 0.f;
    for (int m = 0; m < N_; ++m)
        acc += __bfloat162float(vb[(size_t)m * C_ + c]) * arow[m];

    size_t oi = ((size_t)b * C_ + c) * N_ + n;
    out[oi] = g * acc + out[oi];
}

// ---------------------------------------------------------------------------
extern "C" void kernel_launch(void* const* d_in, const int* in_sizes, int n_in,
                              void* d_out, int out_size, void* d_ws, size_t ws_size,
                              hipStream_t stream)
{
    const float* x     = (const float*)d_in[0];
    const float* gamma = (const float*)d_in[1];

    float* out = (float*)d_out;                       // [B][C][N]  (4,194,304 f32)
    float* att = out + (size_t)B_ * C_ * N_;          // [B][N][N]  (134,217,728 f32)
    __hip_bfloat16* vT = (__hip_bfloat16*)d_ws;       // [B][N][C]  bf16, 8 MB
    float* rsum = (float*)(vT + (size_t)B_ * N_ * C_); // [B][N] f32, 128 KB

    chan_softmax<<<(B_ * N_) / 256, 256, 0, stream>>>(x, out, vT, rsum);
    rsum_sym<<<64 * B_, 256, 0, stream>>>(vT, rsum);
    att_write<<<(N_ / 32) * B_, 256, 0, stream>>>(vT, rsum, att);
    pv_update<<<dim3(N_, B_), C_, 0, stream>>>(gamma, vT, att, out);
}